// Round 17
// baseline (810.345 us; speedup 1.0000x reference)
//
#include <hip/hip_runtime.h>
#include <math.h>

#define BB 4
#define NN 4096
#define DD 128
#define KK 8
#define NBLK 12

typedef __attribute__((ext_vector_type(8))) short short8;
typedef __attribute__((ext_vector_type(4))) float f32x4;

__device__ inline ushort bf16_rn(float x) {
    uint u = __float_as_uint(x);
    u = (u + 0x7FFFu + ((u >> 16) & 1u)) >> 16;
    return (ushort)u;
}
__device__ inline float bf16_f(ushort h) { return __uint_as_float(((uint)h) << 16); }

// ---------------- kNN: R15 version (92us, occ 49%, VALUBusy ~100%) --------
__global__ __launch_bounds__(512) void knn_kernel(const float* __restrict__ xyz,
                                                  int* __restrict__ idx) {
    __shared__ float xs[NN], ys[NN], zs[NN];
    const int b = blockIdx.y;
    const float* xb = xyz + (size_t)b * 3 * NN;
    for (int i = threadIdx.x; i < NN; i += 512) {
        xs[i] = xb[i];
        ys[i] = xb[NN + i];
        zs[i] = xb[2 * NN + i];
    }
    __syncthreads();

    const int wave = threadIdx.x >> 6;
    const int lane = threadIdx.x & 63;
    const int n = blockIdx.x * 8 + wave;
    const float qx = xs[n], qy = ys[n], qz = zs[n];
    const float qsq = __fadd_rn(__fadd_rn(__fmul_rn(qx, qx), __fmul_rn(qy, qy)),
                                __fmul_rn(qz, qz));

    float d[KK];
    int id[KK];
#pragma unroll
    for (int j = 0; j < KK; ++j) { d[j] = INFINITY; id[j] = -1; }

    for (int j = 0; j < NN / 256; ++j) {
        const int m0 = j * 256 + lane * 4;
        const float4 vx = *(const float4*)&xs[m0];
        const float4 vy = *(const float4*)&ys[m0];
        const float4 vz = *(const float4*)&zs[m0];
#pragma unroll
        for (int e = 0; e < 4; ++e) {
            const float cx = (&vx.x)[e], cy = (&vy.x)[e], cz = (&vz.x)[e];
            const float cq = __fadd_rn(__fadd_rn(__fmul_rn(cx, cx),
                                                 __fmul_rn(cy, cy)),
                                       __fmul_rn(cz, cz));
            float inner = __fadd_rn(__fadd_rn(__fmul_rn(qx, cx),
                                              __fmul_rn(qy, cy)),
                                    __fmul_rn(qz, cz));
            float dist = __fadd_rn(__fsub_rn(qsq, __fmul_rn(2.0f, inner)), cq);
            if (dist < d[KK - 1]) {
                d[KK - 1] = dist; id[KK - 1] = m0 + e;
#pragma unroll
                for (int t = KK - 1; t > 0; --t) {
                    if (d[t] < d[t - 1]) {
                        float td = d[t]; d[t] = d[t - 1]; d[t - 1] = td;
                        int ti = id[t]; id[t] = id[t - 1]; id[t - 1] = ti;
                    }
                }
            }
        }
    }

    int out[KK];
#pragma unroll
    for (int it = 0; it < KK; ++it) {
        float hd = d[0];
        int hi = id[0];
#pragma unroll
        for (int s = 32; s; s >>= 1) {
            float od = __shfl_xor(hd, s, 64);
            int oi = __shfl_xor(hi, s, 64);
            if (od < hd || (od == hd && oi < hi)) { hd = od; hi = oi; }
        }
        out[it] = hi;
        if (hd == d[0] && hi == id[0]) {
#pragma unroll
            for (int t = 0; t < KK - 1; ++t) { d[t] = d[t + 1]; id[t] = id[t + 1]; }
            d[KK - 1] = INFINITY; id[KK - 1] = -1;
        }
    }

    if (lane == 0) {
        int* op = idx + ((size_t)b * NN + n) * KK;
        *(int4*)op       = make_int4(out[0], out[1], out[2], out[3]);
        *(int4*)(op + 4) = make_int4(out[4], out[5], out[6], out[7]);
    }
}

// ---------------- weight prep: Wcat = [W1 | W2] split to bf16 hi/lo -------
__global__ __launch_bounds__(256) void prep_w(const float* __restrict__ w1,
                                              const float* __restrict__ w2,
                                              ushort* __restrict__ whi,
                                              ushort* __restrict__ wlo) {
    const int e = blockIdx.x * 256 + threadIdx.x;     // l*32768 + r*256 + k
    const int l = e >> 15;
    const int rem = e & 32767;
    const int r = rem >> 8;
    const int k = rem & 255;
    float w = (k < 128) ? w1[((size_t)l * 128 + r) * 128 + k]
                        : w2[((size_t)l * 128 + r) * 128 + (k - 128)];
    ushort h = bf16_rn(w);
    whi[e] = h;
    wlo[e] = bf16_rn(w - bf16_f(h));
}

// ---------------- initial transpose: ptsT[b][n][c] = points[b][c][n] ------
__global__ __launch_bounds__(256) void transpose_pts(const float* __restrict__ pts,
                                                     float* __restrict__ ptsT) {
    __shared__ float t[32][33];
    const int b = blockIdx.z;
    const int c0 = blockIdx.y * 32;
    const int n0 = blockIdx.x * 32;
    const int tx = threadIdx.x & 31;
    const int ty = threadIdx.x >> 5;
#pragma unroll
    for (int q = 0; q < 4; ++q)
        t[ty + 8 * q][tx] = pts[((size_t)b * DD + c0 + ty + 8 * q) * NN + n0 + tx];
    __syncthreads();
#pragma unroll
    for (int q = 0; q < 4; ++q)
        ptsT[((size_t)b * NN + n0 + ty + 8 * q) * DD + c0 + tx] = t[tx][ty + 8 * q];
}

// ---------------- persistent fused chain: all 12 iterations in one launch -
// 32 cols x 128 rows per block, 512 threads (8 waves), grid 512 (2/CU,
// co-resident). Arithmetic identical to R13/R16. Between iterations:
// per-batch device-scope barrier (fence + atomic arrive + spin + fence).
__global__ __launch_bounds__(512, 4) void fused_chain(float* __restrict__ pT0,
                                                      float* __restrict__ pT1,
                                                      const int* __restrict__ idx,
                                                      const ushort* __restrict__ whi,
                                                      const ushort* __restrict__ wlo,
                                                      float* __restrict__ out_std,
                                                      const float* __restrict__ wc,
                                                      const float* __restrict__ wn,
                                                      const float* __restrict__ xyz,
                                                      float* __restrict__ out_xyz,
                                                      unsigned int* ctr) {
    __shared__ __align__(16) char xt[32768];
    __shared__ float sc[32][132];
    char* xt_hi = xt;
    char* xt_lo = xt + 16384;

    const int bid = blockIdx.x;
    const int xcd = bid & 7;
    const int b = xcd >> 1;                         // 2 XCDs per batch (heuristic only)
    const int colbase = (((xcd & 1) << 6) + (bid >> 3)) * 32;

    const int w = threadIdx.x >> 6;                 // 0..7
    const int lane = threadIdx.x & 63;
    const int half = lane >> 5;                     // row within pair
    const int l32 = lane & 31;                      // channel group (4 ch)
    const int choff = 4 * l32;
    const int row0 = w * 4;                         // wave owns 4 rows

    // idx for this wave's 4 rows — constant across iterations (hoisted)
    const int iv = idx[((size_t)b * NN + colbase + row0) * KK + (lane & 31)];

    const int ln15 = lane & 15;
    const int kl = lane >> 4;

    for (int it = 0; it < NBLK; ++it) {
        const float* baseT = (it & 1 ? pT1 : pT0) + (size_t)b * NN * DD;
        float* outT = (it & 1 ? pT0 : pT1);
        const ushort* whi_i = whi + (size_t)it * 32768;
        const ushort* wlo_i = wlo + (size_t)it * 32768;
        const int last = (it == NBLK - 1);

        // ---- phase A: gather (float4, 2 rows/step, 2 steps) ----
#pragma unroll
        for (int i = 0; i < 2; ++i) {
            const int n_loc = row0 + 2 * i + half;
            const int n = colbase + n_loc;

            int nb[KK];
#pragma unroll
            for (int j = 0; j < KK; ++j) nb[j] = __shfl(iv, (2 * i + half) * 8 + j, 64);

            const float4 c4 = *(const float4*)(baseT + (size_t)n * DD + choff);
            float4 u[KK];
#pragma unroll
            for (int j = 0; j < KK; ++j)
                u[j] = *(const float4*)(baseT + (size_t)nb[j] * DD + choff);

            float g0 = 0.f, g1 = 0.f, g2 = 0.f, g3 = 0.f;
#pragma unroll
            for (int j = 0; j < KK; ++j) {
                g0 += fmaxf(u[j].x, 0.f);
                g1 += fmaxf(u[j].y, 0.f);
                g2 += fmaxf(u[j].z, 0.f);
                g3 += fmaxf(u[j].w, 0.f);
            }
            const float p0 = fmaxf(c4.x, 0.f);
            const float p1 = fmaxf(c4.y, 0.f);
            const float p2 = fmaxf(c4.z, 0.f);
            const float p3 = fmaxf(c4.w, 0.f);

            *(float4*)&sc[n_loc][choff] = c4;       // shortcut cache (pre-relu)

            ushort ph0 = bf16_rn(p0), ph1 = bf16_rn(p1), ph2 = bf16_rn(p2), ph3 = bf16_rn(p3);
            ushort pl0 = bf16_rn(p0 - bf16_f(ph0)), pl1 = bf16_rn(p1 - bf16_f(ph1));
            ushort pl2 = bf16_rn(p2 - bf16_f(ph2)), pl3 = bf16_rn(p3 - bf16_f(ph3));
            ushort gh0 = bf16_rn(g0), gh1 = bf16_rn(g1), gh2 = bf16_rn(g2), gh3 = bf16_rn(g3);
            ushort gl0 = bf16_rn(g0 - bf16_f(gh0)), gl1 = bf16_rn(g1 - bf16_f(gh1));
            ushort gl2 = bf16_rn(g2 - bf16_f(gh2)), gl3 = bf16_rn(g3 - bf16_f(gh3));

            const int gP = l32 >> 1;                // granule 0..15 (P half)
            const int sub = (l32 & 1) << 3;         // byte 0 or 8 in granule
            const int byP = n_loc * 512 + ((gP ^ (n_loc & 7)) << 4) + sub;
            const int byG = n_loc * 512 + (((16 + gP) ^ (n_loc & 7)) << 4) + sub;

            *(unsigned long long*)(xt_hi + byP) =
                (unsigned long long)ph0 | ((unsigned long long)ph1 << 16) |
                ((unsigned long long)ph2 << 32) | ((unsigned long long)ph3 << 48);
            *(unsigned long long*)(xt_lo + byP) =
                (unsigned long long)pl0 | ((unsigned long long)pl1 << 16) |
                ((unsigned long long)pl2 << 32) | ((unsigned long long)pl3 << 48);
            *(unsigned long long*)(xt_hi + byG) =
                (unsigned long long)gh0 | ((unsigned long long)gh1 << 16) |
                ((unsigned long long)gh2 << 32) | ((unsigned long long)gh3 << 48);
            *(unsigned long long*)(xt_lo + byG) =
                (unsigned long long)gl0 | ((unsigned long long)gl1 << 16) |
                ((unsigned long long)gl2 << 32) | ((unsigned long long)gl3 << 48);

            if (last) {                             // fused unpool head
                float s0, s1, s2, s3, s4, s5;
                {
                    const int c0 = choff, c1 = choff + 1, c2 = choff + 2, c3 = choff + 3;
                    s0 = p0 * wc[0 * 128 + c0] + p1 * wc[0 * 128 + c1] + p2 * wc[0 * 128 + c2] + p3 * wc[0 * 128 + c3]
                       + g0 * wn[0 * 128 + c0] + g1 * wn[0 * 128 + c1] + g2 * wn[0 * 128 + c2] + g3 * wn[0 * 128 + c3];
                    s1 = p0 * wc[1 * 128 + c0] + p1 * wc[1 * 128 + c1] + p2 * wc[1 * 128 + c2] + p3 * wc[1 * 128 + c3]
                       + g0 * wn[1 * 128 + c0] + g1 * wn[1 * 128 + c1] + g2 * wn[1 * 128 + c2] + g3 * wn[1 * 128 + c3];
                    s2 = p0 * wc[2 * 128 + c0] + p1 * wc[2 * 128 + c1] + p2 * wc[2 * 128 + c2] + p3 * wc[2 * 128 + c3]
                       + g0 * wn[2 * 128 + c0] + g1 * wn[2 * 128 + c1] + g2 * wn[2 * 128 + c2] + g3 * wn[2 * 128 + c3];
                    s3 = p0 * wc[3 * 128 + c0] + p1 * wc[3 * 128 + c1] + p2 * wc[3 * 128 + c2] + p3 * wc[3 * 128 + c3]
                       + g0 * wn[3 * 128 + c0] + g1 * wn[3 * 128 + c1] + g2 * wn[3 * 128 + c2] + g3 * wn[3 * 128 + c3];
                    s4 = p0 * wc[4 * 128 + c0] + p1 * wc[4 * 128 + c1] + p2 * wc[4 * 128 + c2] + p3 * wc[4 * 128 + c3]
                       + g0 * wn[4 * 128 + c0] + g1 * wn[4 * 128 + c1] + g2 * wn[4 * 128 + c2] + g3 * wn[4 * 128 + c3];
                    s5 = p0 * wc[5 * 128 + c0] + p1 * wc[5 * 128 + c1] + p2 * wc[5 * 128 + c2] + p3 * wc[5 * 128 + c3]
                       + g0 * wn[5 * 128 + c0] + g1 * wn[5 * 128 + c1] + g2 * wn[5 * 128 + c2] + g3 * wn[5 * 128 + c3];
                }
#pragma unroll
                for (int st = 16; st; st >>= 1) {   // reduce within 32-lane group
                    s0 += __shfl_xor(s0, st, 64);
                    s1 += __shfl_xor(s1, st, 64);
                    s2 += __shfl_xor(s2, st, 64);
                    s3 += __shfl_xor(s3, st, 64);
                    s4 += __shfl_xor(s4, st, 64);
                    s5 += __shfl_xor(s5, st, 64);
                }
                if (l32 < 6) {
                    float v = s0;
                    v = (l32 == 1) ? s1 : v;
                    v = (l32 == 2) ? s2 : v;
                    v = (l32 == 3) ? s3 : v;
                    v = (l32 == 4) ? s4 : v;
                    v = (l32 == 5) ? s5 : v;
                    const int dd = l32 >> 1, h = l32 & 1;
                    const float xv = xyz[((size_t)b * 3 + dd) * NN + n];
                    out_xyz[(((size_t)b * 3 + dd) * 2 + h) * NN + n] =
                        v * (1.0f / 9.0f) + xv;
                }
            }
        }
        __syncthreads();

        // ---- phase B: MFMA, per-ks fused 3-combo ----
        const int wrow = w * 16 + ln15;
        f32x4 acc[2] = {};
#pragma unroll
        for (int ks = 0; ks < 8; ++ks) {
            const short8 a_hi = *(const short8*)(whi_i + (size_t)wrow * 256 + ks * 32 + kl * 8);
            const short8 a_lo = *(const short8*)(wlo_i + (size_t)wrow * 256 + ks * 32 + kl * 8);
            short8 bfh[2], bfl[2];
#pragma unroll
            for (int nt = 0; nt < 2; ++nt) {
                const int n_loc = nt * 16 + ln15;
                const int by = n_loc * 512 + (((ks * 4 + kl) ^ (n_loc & 7)) << 4);
                bfh[nt] = *(const short8*)(xt_hi + by);
                bfl[nt] = *(const short8*)(xt_lo + by);
            }
#pragma unroll
            for (int nt = 0; nt < 2; ++nt) {
                acc[nt] = __builtin_amdgcn_mfma_f32_16x16x32_bf16(a_hi, bfh[nt], acc[nt], 0, 0, 0);
                acc[nt] = __builtin_amdgcn_mfma_f32_16x16x32_bf16(a_hi, bfl[nt], acc[nt], 0, 0, 0);
                acc[nt] = __builtin_amdgcn_mfma_f32_16x16x32_bf16(a_lo, bfh[nt], acc[nt], 0, 0, 0);
            }
        }

        // ---- phase C: epilogue: out = acc/9 + shortcut (from LDS) ----
        const float inv = 1.0f / 9.0f;
        const int orow = w * 16 + kl * 4;
#pragma unroll
        for (int nt = 0; nt < 2; ++nt) {
            const int nl = nt * 16 + ln15;
            const int n = colbase + nl;
            const float4 scv = *(const float4*)&sc[nl][orow];
            float v0 = acc[nt][0] * inv + scv.x;
            float v1 = acc[nt][1] * inv + scv.y;
            float v2 = acc[nt][2] * inv + scv.z;
            float v3 = acc[nt][3] * inv + scv.w;
            if (!last) {
                *(float4*)(outT + ((size_t)b * NN + n) * DD + orow) =
                    make_float4(v0, v1, v2, v3);
            } else {
                out_std[((size_t)b * DD + orow + 0) * NN + n] = v0;
                out_std[((size_t)b * DD + orow + 1) * NN + n] = v1;
                out_std[((size_t)b * DD + orow + 2) * NN + n] = v2;
                out_std[((size_t)b * DD + orow + 3) * NN + n] = v3;
            }
        }

        // ---- per-batch device-scope barrier (release/acquire) ----
        if (it < NBLK - 1) {
            __syncthreads();                        // drains each wave's vmcnt
            if (threadIdx.x == 0) {
                __threadfence();                    // release: L2 writeback to coherent point
                atomicAdd(&ctr[it * 4 + b], 1u);
                while (atomicAdd(&ctr[it * 4 + b], 0u) < 128u)
                    __builtin_amdgcn_s_sleep(32);
                __threadfence();                    // acquire: invalidate stale cache lines
            }
            __syncthreads();
        }
    }
}

extern "C" void kernel_launch(void* const* d_in, const int* in_sizes, int n_in,
                              void* d_out, int out_size, void* d_ws, size_t ws_size,
                              hipStream_t stream) {
    const float* xyz    = (const float*)d_in[0];
    const float* points = (const float*)d_in[1];
    const float* w1     = (const float*)d_in[2];
    const float* w2     = (const float*)d_in[3];
    const float* wc     = (const float*)d_in[4];
    const float* wn     = (const float*)d_in[5];
    float* out = (float*)d_out;

    const size_t feat = (size_t)BB * DD * NN;          // 2,097,152 floats
    char* ws = (char*)d_ws;
    int*    idx  = (int*)ws;                            // 512 KB
    ushort* whi  = (ushort*)(ws + 524288);              // 768 KB
    ushort* wlo  = (ushort*)(ws + 1310720);             // 768 KB
    float*  pT0  = (float*)(ws + 2097152);              // 8 MB
    float*  pT1  = pT0 + feat;                          // 8 MB
    unsigned int* ctr = (unsigned int*)(ws + 2097152 + 2 * feat * sizeof(float));

    hipMemsetAsync(ctr, 0, 4 * (NBLK) * sizeof(unsigned int), stream);

    knn_kernel<<<dim3(NN / 8, BB), 512, 0, stream>>>(xyz, idx);
    prep_w<<<dim3(12 * 128 * 256 / 256), 256, 0, stream>>>(w1, w2, whi, wlo);
    transpose_pts<<<dim3(NN / 32, DD / 32, BB), 256, 0, stream>>>(points, pT0);

    float* out_pts = out + (size_t)BB * 3 * 2 * NN;
    fused_chain<<<dim3(512), 512, 0, stream>>>(
        pT0, pT1, idx, whi, wlo, out_pts, wc, wn, xyz, out, ctr);
}

// Round 18
// 276.271 us; speedup vs baseline: 2.9331x; 2.9331x over previous
//
#include <hip/hip_runtime.h>
#include <math.h>

#define BB 4
#define NN 4096
#define DD 128
#define KK 8
#define NBLK 12

typedef __attribute__((ext_vector_type(8))) short short8;
typedef __attribute__((ext_vector_type(4))) float f32x4;

__device__ inline ushort bf16_rn(float x) {
    uint u = __float_as_uint(x);
    u = (u + 0x7FFFu + ((u >> 16) & 1u)) >> 16;
    return (ushort)u;
}
__device__ inline float bf16_f(ushort h) { return __uint_as_float(((uint)h) << 16); }

// ---------------- kNN: R15 version (92us, occ 49%, VALUBusy ~100%) --------
// R3-exact arithmetic, sq computed on the fly; LDS 48KB -> 3 blocks/CU.
__global__ __launch_bounds__(512) void knn_kernel(const float* __restrict__ xyz,
                                                  int* __restrict__ idx) {
    __shared__ float xs[NN], ys[NN], zs[NN];
    const int b = blockIdx.y;
    const float* xb = xyz + (size_t)b * 3 * NN;
    for (int i = threadIdx.x; i < NN; i += 512) {
        xs[i] = xb[i];
        ys[i] = xb[NN + i];
        zs[i] = xb[2 * NN + i];
    }
    __syncthreads();

    const int wave = threadIdx.x >> 6;
    const int lane = threadIdx.x & 63;
    const int n = blockIdx.x * 8 + wave;
    const float qx = xs[n], qy = ys[n], qz = zs[n];
    const float qsq = __fadd_rn(__fadd_rn(__fmul_rn(qx, qx), __fmul_rn(qy, qy)),
                                __fmul_rn(qz, qz));

    float d[KK];
    int id[KK];
#pragma unroll
    for (int j = 0; j < KK; ++j) { d[j] = INFINITY; id[j] = -1; }

    for (int j = 0; j < NN / 256; ++j) {
        const int m0 = j * 256 + lane * 4;
        const float4 vx = *(const float4*)&xs[m0];
        const float4 vy = *(const float4*)&ys[m0];
        const float4 vz = *(const float4*)&zs[m0];
#pragma unroll
        for (int e = 0; e < 4; ++e) {
            const float cx = (&vx.x)[e], cy = (&vy.x)[e], cz = (&vz.x)[e];
            const float cq = __fadd_rn(__fadd_rn(__fmul_rn(cx, cx),
                                                 __fmul_rn(cy, cy)),
                                       __fmul_rn(cz, cz));
            float inner = __fadd_rn(__fadd_rn(__fmul_rn(qx, cx),
                                              __fmul_rn(qy, cy)),
                                    __fmul_rn(qz, cz));
            float dist = __fadd_rn(__fsub_rn(qsq, __fmul_rn(2.0f, inner)), cq);
            if (dist < d[KK - 1]) {
                d[KK - 1] = dist; id[KK - 1] = m0 + e;
#pragma unroll
                for (int t = KK - 1; t > 0; --t) {
                    if (d[t] < d[t - 1]) {
                        float td = d[t]; d[t] = d[t - 1]; d[t - 1] = td;
                        int ti = id[t]; id[t] = id[t - 1]; id[t - 1] = ti;
                    }
                }
            }
        }
    }

    int out[KK];
#pragma unroll
    for (int it = 0; it < KK; ++it) {
        float hd = d[0];
        int hi = id[0];
#pragma unroll
        for (int s = 32; s; s >>= 1) {
            float od = __shfl_xor(hd, s, 64);
            int oi = __shfl_xor(hi, s, 64);
            if (od < hd || (od == hd && oi < hi)) { hd = od; hi = oi; }
        }
        out[it] = hi;
        if (hd == d[0] && hi == id[0]) {
#pragma unroll
            for (int t = 0; t < KK - 1; ++t) { d[t] = d[t + 1]; id[t] = id[t + 1]; }
            d[KK - 1] = INFINITY; id[KK - 1] = -1;
        }
    }

    if (lane == 0) {
        int* op = idx + ((size_t)b * NN + n) * KK;
        *(int4*)op       = make_int4(out[0], out[1], out[2], out[3]);
        *(int4*)(op + 4) = make_int4(out[4], out[5], out[6], out[7]);
    }
}

// ---------------- weight prep: Wcat = [W1 | W2] split to bf16 hi/lo -------
__global__ __launch_bounds__(256) void prep_w(const float* __restrict__ w1,
                                              const float* __restrict__ w2,
                                              ushort* __restrict__ whi,
                                              ushort* __restrict__ wlo) {
    const int e = blockIdx.x * 256 + threadIdx.x;     // l*32768 + r*256 + k
    const int l = e >> 15;
    const int rem = e & 32767;
    const int r = rem >> 8;
    const int k = rem & 255;
    float w = (k < 128) ? w1[((size_t)l * 128 + r) * 128 + k]
                        : w2[((size_t)l * 128 + r) * 128 + (k - 128)];
    ushort h = bf16_rn(w);
    whi[e] = h;
    wlo[e] = bf16_rn(w - bf16_f(h));
}

// ---------------- initial transpose: ptsT[b][n][c] = points[b][c][n] ------
__global__ __launch_bounds__(256) void transpose_pts(const float* __restrict__ pts,
                                                     float* __restrict__ ptsT) {
    __shared__ float t[32][33];
    const int b = blockIdx.z;
    const int c0 = blockIdx.y * 32;
    const int n0 = blockIdx.x * 32;
    const int tx = threadIdx.x & 31;
    const int ty = threadIdx.x >> 5;
#pragma unroll
    for (int q = 0; q < 4; ++q)
        t[ty + 8 * q][tx] = pts[((size_t)b * DD + c0 + ty + 8 * q) * NN + n0 + tx];
    __syncthreads();
#pragma unroll
    for (int q = 0; q < 4; ++q)
        ptsT[((size_t)b * NN + n0 + ty + 8 * q) * DD + c0 + tx] = t[tx][ty + 8 * q];
}

// ---------------- fused: R13 version (14.2us/iter, best of 5 configs) -----
// 32 cols x 128 rows per block, 512 threads (8 waves), grid 512 (2/CU,
// 16 waves/CU). Phase A: float4 gather, 2 rows/step/wave, 2 steps.
// Phase B: per-ks fused 3-combo MFMA (W hi/lo each read once).
__global__ __launch_bounds__(512, 4) void fused_block(const float* __restrict__ ptsT_in,
                                                      const int* __restrict__ idx,
                                                      const ushort* __restrict__ whi,
                                                      const ushort* __restrict__ wlo,
                                                      float* __restrict__ ptsT_out,
                                                      float* __restrict__ out_std,
                                                      const float* __restrict__ wc,
                                                      const float* __restrict__ wn,
                                                      const float* __restrict__ xyz,
                                                      float* __restrict__ out_xyz,
                                                      const int last) {
    __shared__ __align__(16) char xt[32768];
    __shared__ float sc[32][132];
    char* xt_hi = xt;
    char* xt_lo = xt + 16384;

    const int bid = blockIdx.x;
    const int xcd = bid & 7;
    const int b = xcd >> 1;                         // 2 XCDs per batch
    const int colbase = (((xcd & 1) << 6) + (bid >> 3)) * 32;

    const int w = threadIdx.x >> 6;                 // 0..7
    const int lane = threadIdx.x & 63;
    const int half = lane >> 5;                     // row within pair
    const int l32 = lane & 31;                      // channel group (4 ch)
    const int choff = 4 * l32;
    const int row0 = w * 4;                         // wave owns 4 rows

    const float* baseT = ptsT_in + (size_t)b * NN * DD;

    // idx for this wave's 4 rows (32 ints, duplicated across lane halves)
    const int iv = idx[((size_t)b * NN + colbase + row0) * KK + (lane & 31)];

    const int ln15 = lane & 15;
    const int kl = lane >> 4;

    // ---- phase A: gather (float4, 2 rows/step, 2 steps) ----
#pragma unroll
    for (int i = 0; i < 2; ++i) {
        const int n_loc = row0 + 2 * i + half;
        const int n = colbase + n_loc;

        int nb[KK];
#pragma unroll
        for (int j = 0; j < KK; ++j) nb[j] = __shfl(iv, (2 * i + half) * 8 + j, 64);

        const float4 c4 = *(const float4*)(baseT + (size_t)n * DD + choff);
        float4 u[KK];
#pragma unroll
        for (int j = 0; j < KK; ++j)
            u[j] = *(const float4*)(baseT + (size_t)nb[j] * DD + choff);

        float g0 = 0.f, g1 = 0.f, g2 = 0.f, g3 = 0.f;
#pragma unroll
        for (int j = 0; j < KK; ++j) {
            g0 += fmaxf(u[j].x, 0.f);
            g1 += fmaxf(u[j].y, 0.f);
            g2 += fmaxf(u[j].z, 0.f);
            g3 += fmaxf(u[j].w, 0.f);
        }
        const float p0 = fmaxf(c4.x, 0.f);
        const float p1 = fmaxf(c4.y, 0.f);
        const float p2 = fmaxf(c4.z, 0.f);
        const float p3 = fmaxf(c4.w, 0.f);

        *(float4*)&sc[n_loc][choff] = c4;           // shortcut cache (pre-relu)

        ushort ph0 = bf16_rn(p0), ph1 = bf16_rn(p1), ph2 = bf16_rn(p2), ph3 = bf16_rn(p3);
        ushort pl0 = bf16_rn(p0 - bf16_f(ph0)), pl1 = bf16_rn(p1 - bf16_f(ph1));
        ushort pl2 = bf16_rn(p2 - bf16_f(ph2)), pl3 = bf16_rn(p3 - bf16_f(ph3));
        ushort gh0 = bf16_rn(g0), gh1 = bf16_rn(g1), gh2 = bf16_rn(g2), gh3 = bf16_rn(g3);
        ushort gl0 = bf16_rn(g0 - bf16_f(gh0)), gl1 = bf16_rn(g1 - bf16_f(gh1));
        ushort gl2 = bf16_rn(g2 - bf16_f(gh2)), gl3 = bf16_rn(g3 - bf16_f(gh3));

        const int gP = l32 >> 1;                    // granule 0..15 (P half)
        const int sub = (l32 & 1) << 3;             // byte 0 or 8 in granule
        const int byP = n_loc * 512 + ((gP ^ (n_loc & 7)) << 4) + sub;
        const int byG = n_loc * 512 + (((16 + gP) ^ (n_loc & 7)) << 4) + sub;

        *(unsigned long long*)(xt_hi + byP) =
            (unsigned long long)ph0 | ((unsigned long long)ph1 << 16) |
            ((unsigned long long)ph2 << 32) | ((unsigned long long)ph3 << 48);
        *(unsigned long long*)(xt_lo + byP) =
            (unsigned long long)pl0 | ((unsigned long long)pl1 << 16) |
            ((unsigned long long)pl2 << 32) | ((unsigned long long)pl3 << 48);
        *(unsigned long long*)(xt_hi + byG) =
            (unsigned long long)gh0 | ((unsigned long long)gh1 << 16) |
            ((unsigned long long)gh2 << 32) | ((unsigned long long)gh3 << 48);
        *(unsigned long long*)(xt_lo + byG) =
            (unsigned long long)gl0 | ((unsigned long long)gl1 << 16) |
            ((unsigned long long)gl2 << 32) | ((unsigned long long)gl3 << 48);

        if (last) {                                 // fused unpool head
            float s0, s1, s2, s3, s4, s5;
            {
                const int c0 = choff, c1 = choff + 1, c2 = choff + 2, c3 = choff + 3;
                s0 = p0 * wc[0 * 128 + c0] + p1 * wc[0 * 128 + c1] + p2 * wc[0 * 128 + c2] + p3 * wc[0 * 128 + c3]
                   + g0 * wn[0 * 128 + c0] + g1 * wn[0 * 128 + c1] + g2 * wn[0 * 128 + c2] + g3 * wn[0 * 128 + c3];
                s1 = p0 * wc[1 * 128 + c0] + p1 * wc[1 * 128 + c1] + p2 * wc[1 * 128 + c2] + p3 * wc[1 * 128 + c3]
                   + g0 * wn[1 * 128 + c0] + g1 * wn[1 * 128 + c1] + g2 * wn[1 * 128 + c2] + g3 * wn[1 * 128 + c3];
                s2 = p0 * wc[2 * 128 + c0] + p1 * wc[2 * 128 + c1] + p2 * wc[2 * 128 + c2] + p3 * wc[2 * 128 + c3]
                   + g0 * wn[2 * 128 + c0] + g1 * wn[2 * 128 + c1] + g2 * wn[2 * 128 + c2] + g3 * wn[2 * 128 + c3];
                s3 = p0 * wc[3 * 128 + c0] + p1 * wc[3 * 128 + c1] + p2 * wc[3 * 128 + c2] + p3 * wc[3 * 128 + c3]
                   + g0 * wn[3 * 128 + c0] + g1 * wn[3 * 128 + c1] + g2 * wn[3 * 128 + c2] + g3 * wn[3 * 128 + c3];
                s4 = p0 * wc[4 * 128 + c0] + p1 * wc[4 * 128 + c1] + p2 * wc[4 * 128 + c2] + p3 * wc[4 * 128 + c3]
                   + g0 * wn[4 * 128 + c0] + g1 * wn[4 * 128 + c1] + g2 * wn[4 * 128 + c2] + g3 * wn[4 * 128 + c3];
                s5 = p0 * wc[5 * 128 + c0] + p1 * wc[5 * 128 + c1] + p2 * wc[5 * 128 + c2] + p3 * wc[5 * 128 + c3]
                   + g0 * wn[5 * 128 + c0] + g1 * wn[5 * 128 + c1] + g2 * wn[5 * 128 + c2] + g3 * wn[5 * 128 + c3];
            }
#pragma unroll
            for (int st = 16; st; st >>= 1) {       // reduce within 32-lane group
                s0 += __shfl_xor(s0, st, 64);
                s1 += __shfl_xor(s1, st, 64);
                s2 += __shfl_xor(s2, st, 64);
                s3 += __shfl_xor(s3, st, 64);
                s4 += __shfl_xor(s4, st, 64);
                s5 += __shfl_xor(s5, st, 64);
            }
            if (l32 < 6) {
                float v = s0;
                v = (l32 == 1) ? s1 : v;
                v = (l32 == 2) ? s2 : v;
                v = (l32 == 3) ? s3 : v;
                v = (l32 == 4) ? s4 : v;
                v = (l32 == 5) ? s5 : v;
                const int dd = l32 >> 1, h = l32 & 1;
                const float xv = xyz[((size_t)b * 3 + dd) * NN + n];
                out_xyz[(((size_t)b * 3 + dd) * 2 + h) * NN + n] =
                    v * (1.0f / 9.0f) + xv;
            }
        }
    }
    __syncthreads();

    // ---- phase B: MFMA. wave w: rows w*16..w*16+15, 2 ntiles,
    //      per-ks fused 3-combo (a_hi*x_hi + a_hi*x_lo + a_lo*x_hi) ----
    const int wrow = w * 16 + ln15;
    f32x4 acc[2] = {};
#pragma unroll
    for (int ks = 0; ks < 8; ++ks) {
        const short8 a_hi = *(const short8*)(whi + (size_t)wrow * 256 + ks * 32 + kl * 8);
        const short8 a_lo = *(const short8*)(wlo + (size_t)wrow * 256 + ks * 32 + kl * 8);
        short8 bfh[2], bfl[2];
#pragma unroll
        for (int nt = 0; nt < 2; ++nt) {
            const int n_loc = nt * 16 + ln15;
            const int by = n_loc * 512 + (((ks * 4 + kl) ^ (n_loc & 7)) << 4);
            bfh[nt] = *(const short8*)(xt_hi + by);
            bfl[nt] = *(const short8*)(xt_lo + by);
        }
#pragma unroll
        for (int nt = 0; nt < 2; ++nt) {
            acc[nt] = __builtin_amdgcn_mfma_f32_16x16x32_bf16(a_hi, bfh[nt], acc[nt], 0, 0, 0);
            acc[nt] = __builtin_amdgcn_mfma_f32_16x16x32_bf16(a_hi, bfl[nt], acc[nt], 0, 0, 0);
            acc[nt] = __builtin_amdgcn_mfma_f32_16x16x32_bf16(a_lo, bfh[nt], acc[nt], 0, 0, 0);
        }
    }

    // ---- phase C: epilogue: out = acc/9 + shortcut (from LDS) ----
    const float inv = 1.0f / 9.0f;
    const int orow = w * 16 + kl * 4;
#pragma unroll
    for (int nt = 0; nt < 2; ++nt) {
        const int nl = nt * 16 + ln15;
        const int n = colbase + nl;
        const float4 scv = *(const float4*)&sc[nl][orow];
        float v0 = acc[nt][0] * inv + scv.x;
        float v1 = acc[nt][1] * inv + scv.y;
        float v2 = acc[nt][2] * inv + scv.z;
        float v3 = acc[nt][3] * inv + scv.w;
        if (!last) {
            *(float4*)(ptsT_out + ((size_t)b * NN + n) * DD + orow) =
                make_float4(v0, v1, v2, v3);
        } else {
            out_std[((size_t)b * DD + orow + 0) * NN + n] = v0;
            out_std[((size_t)b * DD + orow + 1) * NN + n] = v1;
            out_std[((size_t)b * DD + orow + 2) * NN + n] = v2;
            out_std[((size_t)b * DD + orow + 3) * NN + n] = v3;
        }
    }
}

extern "C" void kernel_launch(void* const* d_in, const int* in_sizes, int n_in,
                              void* d_out, int out_size, void* d_ws, size_t ws_size,
                              hipStream_t stream) {
    const float* xyz    = (const float*)d_in[0];
    const float* points = (const float*)d_in[1];
    const float* w1     = (const float*)d_in[2];
    const float* w2     = (const float*)d_in[3];
    const float* wc     = (const float*)d_in[4];
    const float* wn     = (const float*)d_in[5];
    float* out = (float*)d_out;

    const size_t feat = (size_t)BB * DD * NN;          // 2,097,152 floats
    char* ws = (char*)d_ws;
    int*    idx  = (int*)ws;                            // 512 KB
    ushort* whi  = (ushort*)(ws + 524288);              // 768 KB
    ushort* wlo  = (ushort*)(ws + 524288 + 786432);     // 768 KB
    float*  pT0  = (float*)(ws + 524288 + 2 * 786432);  // 8 MB
    float*  pT1  = pT0 + feat;                          // 8 MB

    knn_kernel<<<dim3(NN / 8, BB), 512, 0, stream>>>(xyz, idx);
    prep_w<<<dim3(12 * 128 * 256 / 256), 256, 0, stream>>>(w1, w2, whi, wlo);
    transpose_pts<<<dim3(NN / 32, DD / 32, BB), 256, 0, stream>>>(points, pT0);

    float* out_pts = out + (size_t)BB * 3 * 2 * NN;
    float* bufs[2] = {pT0, pT1};
    for (int i = 0; i < NBLK; ++i) {
        const int last = (i == NBLK - 1);
        fused_block<<<dim3(512), 512, 0, stream>>>(
            bufs[i & 1], idx, whi + (size_t)i * 32768, wlo + (size_t)i * 32768,
            bufs[(i + 1) & 1], out_pts, wc, wn, xyz, out, last);
    }
}